// Round 11
// baseline (244.589 us; speedup 1.0000x reference)
//
#include <hip/hip_runtime.h>
#include <hip/hip_bf16.h>

// Problem constants
#define NB 512     // batch
#define NP 1152    // primary capsules
#define NC 10      // digit capsules
#define ND 16      // output capsule dim
#define NI 8       // input capsule dim

constexpr int K_B    = 2;                // b's per lane
constexpr int B_TILE = 4 * 4 * K_B;      // 32 b per block (4 waves x 4 bsub x K_B)
constexpr int P_TILE = 8;                // p's per W tile
constexpr int NPT    = 3;                // R11: W tiles per block (24 p's/block)
constexpr int NBLK_B = NB / B_TILE;      // 16
constexpr int NBLK_P = NP / P_TILE;      // 144 W tiles
constexpr int NBLK_PO = NBLK_P / NPT;    // 48 partial slices
constexpr int SVD = NB * NC * ND;        // 81920
constexpr int W_TILE_BYTES = P_TILE * NC * ND * NI * 4;   // 40960
constexpr int X_TILE_FLOATS = B_TILE * P_TILE * NI;       // 2048 floats = 8KB

constexpr float LOG2E = 1.4426950408889634f;

typedef float v2f __attribute__((ext_vector_type(2)));

// 16-lane all-reduce sum via DPP (quad_perm xor1, xor2; row_ror 4, 8).
// Pure VALU. Result broadcast to all 16 lanes of the row.
__device__ __forceinline__ float red16_dpp(float v) {
    int t;
    t = __builtin_amdgcn_update_dpp(0, __float_as_int(v), 0xB1, 0xF, 0xF, true); // xor1
    v += __int_as_float(t);
    t = __builtin_amdgcn_update_dpp(0, __float_as_int(v), 0x4E, 0xF, 0xF, true); // xor2
    v += __int_as_float(t);
    t = __builtin_amdgcn_update_dpp(0, __float_as_int(v), 0x124, 0xF, 0xF, true); // row_ror:4
    v += __int_as_float(t);
    t = __builtin_amdgcn_update_dpp(0, __float_as_int(v), 0x128, 0xF, 0xF, true); // row_ror:8
    v += __int_as_float(t);
    return v;
}

// 4-lane all-reduce sum via DPP quad_perm (xor1, xor2). Broadcast to quad.
__device__ __forceinline__ float red4_dpp(float v) {
    int t;
    t = __builtin_amdgcn_update_dpp(0, __float_as_int(v), 0xB1, 0xF, 0xF, true); // xor1
    v += __int_as_float(t);
    t = __builtin_amdgcn_update_dpp(0, __float_as_int(v), 0x4E, 0xF, 0xF, true); // xor2
    v += __int_as_float(t);
    return v;
}

// One routing pass. R11: two-stage reduction with COARSER partials.
// R10 evidence: killing atomics dropped passes 73->63us, VALUBusy ->65%
// (atomic tail confirmed as the old floor), but 3x46MB partial write+read
// traffic ate the total-time win. R11: each block loops NPT=3 W tiles
// (stage -> sync -> compute -> sync), accumulating sacc over 24 p's before
// ONE store -> 48 slices (15.7MB), grid 768 = exactly 3 blocks/CU (48KB LDS),
// same 12 waves/CU, vr-prologue amortized 3x.
// Grid swizzle (R9, kept): id%16 = bblk -> per-bblk XCD affinity, x L2-local.
// W LDS swizzle involution: S(A) = A ^ (bit7(A)<<4) ^ (bit8(A)<<5).
// x LDS swizzle (R4, verified): physical unit u holds logical (bl, w16^(bl&3))
//   -> read XOR (bsub<<4): bsub hits bank-quads {0,4,8,12}, conflict-free.
// Softmax slimming (R2, verified): log2(e) folded into vr, NO max-subtraction
// (|lg*log2e| <~ 50 << 127, exp2-safe), v_rcp_f32 for 1/sum.
// VGPR-cap law (confirmed 4x): bounds(_,N) -> cap 256/N; (256,2) -> 128 >>
// demand ~80 -> no spill; HW residency LDS-capped at 3 blocks/CU.
// PASS 0: coup = 0.1;  PASS 1: logits = u.v0;  PASS 2: logits = u.(v0+v1)
template<int PASS, bool TS>
__global__ __launch_bounds__(256, 2)
void caps_pass(const float* __restrict__ x,    // [NB, NP, NI]
               const float* __restrict__ w,    // [NP, NC, ND, NI]
               const float* __restrict__ v0,   // [NB, NC, ND]
               const float* __restrict__ v1,   // [NB, NC, ND]
               float* __restrict__ s_out)      // TS: partial[NBLK_PO][SVD]; else s[SVD]
{
    __shared__ __align__(16) float w_lds[W_TILE_BYTES / 4];   // 40KB
    __shared__ __align__(16) float x_lds[X_TILE_FLOATS];      // 8KB, [b][pp][i] swizzled

    const int tid  = threadIdx.x;
    const int lane = tid & 63;
    const int wave = tid >> 6;           // 0..3
    const int d    = lane & 15;
    const int bsub = lane >> 4;          // 0..3
    // R9 swizzle: id = pblk_out*16 + bblk -> id%8 = bblk%8 -> XCD affinity.
    const int bblk     = blockIdx.x % NBLK_B;
    const int pblk_out = blockIdx.x / NBLK_B;   // 0..47

    // W source swizzle offset: S(lane*16) within each 1KB chunk
    const int lane_src = (lane << 4) ^ ((lane & 8) << 1) ^ ((lane & 16) << 1);

    int bidx[K_B];
    #pragma unroll
    for (int k = 0; k < K_B; ++k) bidx[k] = bblk * B_TILE + wave * 8 + k * 4 + bsub;

    // v (v0, or v0+v1 for pass 2), pre-scaled by log2(e) — loop-invariant
    float vr[K_B][NC];
    if (PASS >= 1) {
        #pragma unroll
        for (int k = 0; k < K_B; ++k)
            #pragma unroll
            for (int c = 0; c < NC; ++c) {
                float vv = v0[(bidx[k] * NC + c) * ND + d];
                if (PASS == 2) vv += v1[(bidx[k] * NC + c) * ND + d];
                vr[k][c] = vv * LOG2E;
            }
    }

    float sacc[K_B][NC];
    #pragma unroll
    for (int k = 0; k < K_B; ++k)
        #pragma unroll
        for (int c = 0; c < NC; ++c) sacc[k][c] = 0.0f;

    // swizzled read offset for W[pp,c,d,0:4]: A = d*32 -> A ^ (bit2(d)<<4) ^ (bit3(d)<<5)
    const int lane_rd = (d << 5) ^ ((d & 4) << 2) ^ ((d & 8) << 2);
    const int xswz    = bsub << 4;   // x read swizzle (byte bits 4-5 ^= b&3)

    for (int tt = 0; tt < NPT; ++tt) {
        const int pblk = pblk_out * NPT + tt;
        const int p0   = pblk * P_TILE;

        if (tt > 0) __syncthreads();   // all waves done reading previous tile

        // ---- stage W tile (16B/lane, linear dest, swizzled source) ----
        {
            const uint8_t* wsrc = (const uint8_t*)w + (size_t)pblk * W_TILE_BYTES;
            #pragma unroll
            for (int j = 0; j < 10; ++j) {
                const int off = wave * 10240 + j * 1024;
                __builtin_amdgcn_global_load_lds(
                    (const __attribute__((address_space(1))) void*)(wsrc + off + lane_src),
                    (__attribute__((address_space(3))) void*)((uint8_t*)w_lds + off),
                    16, 0, 0);
            }
        }

        // ---- stage x tile: 8KB, linear dest, swizzled source strips ----
        {
            #pragma unroll
            for (int j = 0; j < 2; ++j) {
                const int u   = wave * 128 + j * 64 + lane;
                const int bl  = u >> 4;
                const int w16 = u & 15;
                const float* bbase = x + ((size_t)(bblk * B_TILE + bl) * NP + p0) * NI;
                const uint8_t* src = (const uint8_t*)bbase + ((w16 ^ (bl & 3)) * 16);
                __builtin_amdgcn_global_load_lds(
                    (const __attribute__((address_space(1))) void*)src,
                    (__attribute__((address_space(3))) void*)((uint8_t*)x_lds + (size_t)u * 16),
                    16, 0, 0);
            }
        }

        asm volatile("s_waitcnt vmcnt(0)" ::: "memory");
        __syncthreads();

        for (int pp = 0; pp < P_TILE; ++pp) {
            v2f xv[K_B][4];
            #pragma unroll
            for (int k = 0; k < K_B; ++k) {
                const int xb = ((wave * 8 + k * 4 + bsub) * 256 + pp * 32) ^ xswz;
                const uint8_t* xp = (const uint8_t*)x_lds;
                const float4 a = *(const float4*)(xp + xb);
                const float4 b = *(const float4*)(xp + (xb ^ 16));
                xv[k][0] = v2f{a.x, a.y};
                xv[k][1] = v2f{a.z, a.w};
                xv[k][2] = v2f{b.x, b.y};
                xv[k][3] = v2f{b.z, b.w};
            }

            float uh[K_B][NC];
            #pragma unroll
            for (int c = 0; c < NC; ++c) {
                const uint8_t* pb = (const uint8_t*)w_lds + pp * 5120 + c * 512;
                const float4 wa = *(const float4*)(pb + lane_rd);          // W[p,c,d,0:4]
                const float4 wb = *(const float4*)(pb + (lane_rd ^ 16));   // W[p,c,d,4:8]
                const v2f w01{wa.x, wa.y}, w23{wa.z, wa.w};
                const v2f w45{wb.x, wb.y}, w67{wb.z, wb.w};
                #pragma unroll
                for (int k = 0; k < K_B; ++k) {
                    v2f acc = w01 * xv[k][0];                              // v_pk_mul_f32
                    acc = __builtin_elementwise_fma(w23, xv[k][1], acc);   // v_pk_fma_f32
                    acc = __builtin_elementwise_fma(w45, xv[k][2], acc);
                    acc = __builtin_elementwise_fma(w67, xv[k][3], acc);
                    const float u = acc[0] + acc[1];
                    if (PASS == 0) sacc[k][c] = fmaf(0.1f, u, sacc[k][c]);
                    else           uh[k][c] = u;
                }
            }

            if (PASS >= 1) {
                #pragma unroll
                for (int k = 0; k < K_B; ++k) {
                    float lg[NC];
                    #pragma unroll
                    for (int c = 0; c < NC; ++c)
                        lg[c] = red16_dpp(uh[k][c] * vr[k][c]);   // log2-domain logits
                    float ssum = 0.0f;
                    float coup[NC];
                    #pragma unroll
                    for (int c = 0; c < NC; ++c) {
                        coup[c] = __builtin_amdgcn_exp2f(lg[c]);  // no max-sub: bounded
                        ssum += coup[c];
                    }
                    const float inv = __builtin_amdgcn_rcpf(ssum);
                    #pragma unroll
                    for (int c = 0; c < NC; ++c)
                        sacc[k][c] = fmaf(coup[c] * inv, uh[k][c], sacc[k][c]);
                }
            }
        }
    }

    // tail: each thread owns distinct (b,d). TS: plain stores into this
    // pblk_out's private slice (fire-and-forget). Legacy: device atomics.
    if (TS) {
        float* pout = s_out + (size_t)pblk_out * SVD;
        #pragma unroll
        for (int k = 0; k < K_B; ++k)
            #pragma unroll
            for (int c = 0; c < NC; ++c)
                pout[(bidx[k] * NC + c) * ND + d] = sacc[k][c];
    } else {
        #pragma unroll
        for (int k = 0; k < K_B; ++k)
            #pragma unroll
            for (int c = 0; c < NC; ++c)
                atomicAdd(&s_out[(bidx[k] * NC + c) * ND + d], sacc[k][c]);
    }
}

// R11: fused reduce (sum over 48 pblk slices) + squash, float4-vectorized.
// Thread g handles 4 consecutive floats (base = g*4); a d-row (16 floats) =
// 4 consecutive threads = one lane-quad -> 4-lane DPP reduce for |s|^2.
// 15.7MB reads, coalesced 1KB/wave/instr, mostly L2/L3-resident.
__global__ __launch_bounds__(256)
void caps_reduce_squash(const float* __restrict__ part, float* __restrict__ v)
{
    const int g = blockIdx.x * 256 + threadIdx.x;     // 0 .. SVD/4-1
    const float4* p4 = (const float4*)part;
    float4 a0{0,0,0,0}, a1{0,0,0,0}, a2{0,0,0,0}, a3{0,0,0,0};
    #pragma unroll
    for (int r = 0; r < NBLK_PO; r += 4) {
        const float4 t0 = p4[(size_t)(r + 0) * (SVD / 4) + g];
        const float4 t1 = p4[(size_t)(r + 1) * (SVD / 4) + g];
        const float4 t2 = p4[(size_t)(r + 2) * (SVD / 4) + g];
        const float4 t3 = p4[(size_t)(r + 3) * (SVD / 4) + g];
        a0.x += t0.x; a0.y += t0.y; a0.z += t0.z; a0.w += t0.w;
        a1.x += t1.x; a1.y += t1.y; a1.z += t1.z; a1.w += t1.w;
        a2.x += t2.x; a2.y += t2.y; a2.z += t2.z; a2.w += t2.w;
        a3.x += t3.x; a3.y += t3.y; a3.z += t3.z; a3.w += t3.w;
    }
    float4 sv;
    sv.x = (a0.x + a1.x) + (a2.x + a3.x);
    sv.y = (a0.y + a1.y) + (a2.y + a3.y);
    sv.z = (a0.z + a1.z) + (a2.z + a3.z);
    sv.w = (a0.w + a1.w) + (a2.w + a3.w);
    const float sql = ((sv.x * sv.x + sv.y * sv.y) + (sv.z * sv.z + sv.w * sv.w));
    const float sq  = red4_dpp(sql);                  // sum over the d-row's quad
    const float scale = (sq / (1.0f + sq)) / sqrtf(sq + 1e-7f);
    sv.x *= scale; sv.y *= scale; sv.z *= scale; sv.w *= scale;
    ((float4*)v)[g] = sv;
}

// Legacy squash (fallback path). ZERO_S re-zeros s for the next pass.
template<bool ZERO_S>
__global__ __launch_bounds__(256)
void caps_squash(float* __restrict__ s, float* __restrict__ v)
{
    const int idx = blockIdx.x * 256 + threadIdx.x;
    const float sv = s[idx];
    if (ZERO_S) s[idx] = 0.0f;
    float sq = red16_dpp(sv * sv);
    const float scale = (sq / (1.0f + sq)) / sqrtf(sq + 1e-7f);
    v[idx] = scale * sv;
}

extern "C" void kernel_launch(void* const* d_in, const int* in_sizes, int n_in,
                              void* d_out, int out_size, void* d_ws, size_t ws_size,
                              hipStream_t stream)
{
    const float* x = (const float*)d_in[0];
    const float* w = (const float*)d_in[1];
    float* out = (float*)d_out;

    const dim3 pgrid(NBLK_B * NBLK_PO);  // 768 blocks of 256 (3/CU exactly)
    const dim3 pblock(256);
    const dim3 rgrid(SVD / 4 / 256);     // 80
    const dim3 rblock(256);

    const size_t partBytes = (size_t)NBLK_PO * SVD * sizeof(float);  // ~15.7MB

    if (ws_size >= partBytes + (size_t)SVD * sizeof(float)) {
        // ---- two-stage path: no atomics, no memset ----
        float* part = (float*)d_ws;                                  // [NBLK_PO][SVD]
        float* v0   = (float*)((uint8_t*)d_ws + partBytes);          // [SVD]
        float* v1   = out;                                           // reuse output

        caps_pass<0, true><<<pgrid, pblock, 0, stream>>>(x, w, nullptr, nullptr, part);
        caps_reduce_squash<<<rgrid, rblock, 0, stream>>>(part, v0);
        caps_pass<1, true><<<pgrid, pblock, 0, stream>>>(x, w, v0, nullptr, part);
        caps_reduce_squash<<<rgrid, rblock, 0, stream>>>(part, v1);
        caps_pass<2, true><<<pgrid, pblock, 0, stream>>>(x, w, v0, v1, part);
        caps_reduce_squash<<<rgrid, rblock, 0, stream>>>(part, out);
    } else {
        // ---- fallback: atomic path ----
        float* s  = (float*)d_ws;       // [SVD]
        float* v0 = s + SVD;            // [SVD]
        float* v1 = out;
        const dim3 qgrid(SVD / 256);    // 320
        const dim3 qblock(256);

        hipMemsetAsync(s, 0, (size_t)SVD * sizeof(float), stream);
        caps_pass<0, false><<<pgrid, pblock, 0, stream>>>(x, w, nullptr, nullptr, s);
        caps_squash<true><<<qgrid, qblock, 0, stream>>>(s, v0);
        caps_pass<1, false><<<pgrid, pblock, 0, stream>>>(x, w, v0, nullptr, s);
        caps_squash<true><<<qgrid, qblock, 0, stream>>>(s, v1);
        caps_pass<2, false><<<pgrid, pblock, 0, stream>>>(x, w, v0, v1, s);
        caps_squash<false><<<qgrid, qblock, 0, stream>>>(s, out);
    }
}